// Round 1
// baseline (857.079 us; speedup 1.0000x reference)
//
#include <hip/hip_runtime.h>
#include <hip/hip_bf16.h>

#define NN   100000
#define EE   3200000
#define HH   32
#define BB   128
#define KMAX 96

// ws layout (bytes)
static constexpr size_t Q_OFF      = 0;           // N*32 f32 = 12.8 MB
static constexpr size_t AGG_OFF    = 12800000;    // N*32 f32
static constexpr size_t H_OFF      = 25600000;    // N*32 f32
static constexpr size_t CSR_OFF    = 38400000;    // N*96 int = 38.4 MB
static constexpr size_t CNT_OFF    = 76800000;    // N int
static constexpr size_t STATS_OFF  = 77200000;    // 64 f32: sum[32], sumsq[32]
static constexpr size_t BNAB_OFF   = 77200256;    // 64 f32: a[32], c[32]
static constexpr size_t POOLED_OFF = 77200512;    // B*32 f32
static constexpr size_t PCNT_OFF   = 77216896;    // B f32
static constexpr size_t ZERO_BYTES = 417408;      // CNT..PCNT end, one memset

// ---- CSR build: one pass, padded buckets (deg ~ Poisson(32), P(deg>=96) ~ 1e-20)
__global__ __launch_bounds__(256) void build_csr_kernel(const int* __restrict__ ei,
                                                        int* __restrict__ cnt,
                                                        int* __restrict__ csr) {
    int e = blockIdx.x * 256 + threadIdx.x;
    if (e >= EE) return;
    int s = ei[e];        // row 0 = src
    int d = ei[EE + e];   // row 1 = dst
    int slot = atomicAdd(&cnt[d], 1);
    if (slot < KMAX) csr[(size_t)d * KMAX + slot] = s;
}

// ---- projection q = h @ w1 ; agg = q + b1. For FIN==32, fold previous BN affine
// (h -> h*a + c) into the load. Block 0 zeroes the stats accumulator for this layer.
template <int FIN>
__global__ __launch_bounds__(256) void proj_kernel(const float* __restrict__ hin,
                                                   const float* __restrict__ w1,
                                                   const float* __restrict__ b1,
                                                   const float* __restrict__ bnab,
                                                   float* __restrict__ q,
                                                   float* __restrict__ agg,
                                                   float* __restrict__ stats) {
    int tid = threadIdx.x;
    if (blockIdx.x == 0 && tid < 64) stats[tid] = 0.f;
    int n = blockIdx.x * 256 + tid;
    if (n >= NN) return;
    float acc[32];
#pragma unroll
    for (int c = 0; c < 32; c++) acc[c] = 0.f;
    const float4* h4 = (const float4*)(hin + (size_t)n * FIN);
    for (int jj = 0; jj < FIN; jj += 32) {
        float hv[32];
#pragma unroll
        for (int k = 0; k < 8; k++) {
            float4 v = h4[jj / 4 + k];
            hv[4 * k] = v.x; hv[4 * k + 1] = v.y; hv[4 * k + 2] = v.z; hv[4 * k + 3] = v.w;
        }
        if constexpr (FIN == 32) {
#pragma unroll
            for (int j = 0; j < 32; j++) hv[j] = fmaf(hv[j], bnab[j], bnab[32 + j]);
        }
#pragma unroll 4
        for (int j = 0; j < 32; j++) {
            float hvj = hv[j];
            const float* wrow = w1 + (size_t)(jj + j) * 32;  // uniform -> scalar loads
#pragma unroll
            for (int c = 0; c < 32; c++) acc[c] = fmaf(hvj, wrow[c], acc[c]);
        }
    }
    float4* qr = (float4*)(q + (size_t)n * 32);
    float4* ar = (float4*)(agg + (size_t)n * 32);
#pragma unroll
    for (int k = 0; k < 8; k++) {
        float4 qv; qv.x = acc[4*k]; qv.y = acc[4*k+1]; qv.z = acc[4*k+2]; qv.w = acc[4*k+3];
        float4 av; av.x = qv.x + b1[4*k]; av.y = qv.y + b1[4*k+1];
        av.z = qv.z + b1[4*k+2]; av.w = qv.w + b1[4*k+3];
        qr[k] = qv; ar[k] = av;
    }
}

// ---- gather: agg[n] += sum over in-edges of q[src]. 8 threads per node (float4 parts),
// coalesced 128B row reads, no atomics.
__global__ __launch_bounds__(256) void gather_kernel(const float4* __restrict__ q4,
                                                     const int* __restrict__ csr,
                                                     const int* __restrict__ cnt,
                                                     float4* __restrict__ agg4) {
    int t = blockIdx.x * 256 + threadIdx.x;
    int n = t >> 3;
    if (n >= NN) return;
    int p = t & 7;
    int d = min(cnt[n], KMAX);
    const int* lst = csr + (size_t)n * KMAX;
    float ax = 0.f, ay = 0.f, az = 0.f, aw = 0.f;
    int i = 0;
    for (; i + 4 <= d; i += 4) {  // 4 loads in flight
        int s0 = lst[i], s1 = lst[i + 1], s2 = lst[i + 2], s3 = lst[i + 3];
        float4 v0 = q4[(size_t)s0 * 8 + p];
        float4 v1 = q4[(size_t)s1 * 8 + p];
        float4 v2 = q4[(size_t)s2 * 8 + p];
        float4 v3 = q4[(size_t)s3 * 8 + p];
        ax += (v0.x + v1.x) + (v2.x + v3.x);
        ay += (v0.y + v1.y) + (v2.y + v3.y);
        az += (v0.z + v1.z) + (v2.z + v3.z);
        aw += (v0.w + v1.w) + (v2.w + v3.w);
    }
    for (; i < d; i++) {
        int s = lst[i];
        float4 v = q4[(size_t)s * 8 + p];
        ax += v.x; ay += v.y; az += v.z; aw += v.w;
    }
    float4 a = agg4[(size_t)n * 8 + p];
    a.x += ax; a.y += ay; a.z += az; a.w += aw;
    agg4[(size_t)n * 8 + p] = a;
}

// ---- MLP tail: u = relu(agg); v = u@w2 + b2; r = relu(v); write r; accumulate BN stats.
__global__ __launch_bounds__(256) void mlp_kernel(const float* __restrict__ agg,
                                                  const float* __restrict__ w2,
                                                  const float* __restrict__ b2,
                                                  float* __restrict__ r,
                                                  float* __restrict__ stats) {
    __shared__ float tile[256 * 33];  // +1 pad -> conflict-free columns
    __shared__ float ps[8 * 32];
    __shared__ float pq[8 * 32];
    int tid = threadIdx.x;
    int n = blockIdx.x * 256 + tid;
    float rc[32];
    if (n < NN) {
        float u[32];
        const float4* a4 = (const float4*)(agg + (size_t)n * 32);
#pragma unroll
        for (int k = 0; k < 8; k++) {
            float4 v = a4[k];
            u[4*k]   = fmaxf(v.x, 0.f);
            u[4*k+1] = fmaxf(v.y, 0.f);
            u[4*k+2] = fmaxf(v.z, 0.f);
            u[4*k+3] = fmaxf(v.w, 0.f);
        }
#pragma unroll
        for (int c = 0; c < 32; c++) rc[c] = b2[c];
#pragma unroll 4
        for (int j = 0; j < 32; j++) {
            float uj = u[j];
            const float* wrow = w2 + (size_t)j * 32;
#pragma unroll
            for (int c = 0; c < 32; c++) rc[c] = fmaf(uj, wrow[c], rc[c]);
        }
#pragma unroll
        for (int c = 0; c < 32; c++) rc[c] = fmaxf(rc[c], 0.f);
        float4* rr = (float4*)(r + (size_t)n * 32);
#pragma unroll
        for (int k = 0; k < 8; k++) {
            float4 v; v.x = rc[4*k]; v.y = rc[4*k+1]; v.z = rc[4*k+2]; v.w = rc[4*k+3];
            rr[k] = v;
        }
    } else {
#pragma unroll
        for (int c = 0; c < 32; c++) rc[c] = 0.f;
    }
#pragma unroll
    for (int c = 0; c < 32; c++) tile[tid * 33 + c] = rc[c];
    __syncthreads();
    {   // phase 1: 8 row-blocks x 32 columns of partials
        int c = tid & 31, rb = tid >> 5;
        float s = 0.f, sq = 0.f;
        for (int it = 0; it < 32; it++) {
            float v = tile[(rb * 32 + it) * 33 + c];
            s += v; sq += v * v;
        }
        ps[rb * 32 + c] = s; pq[rb * 32 + c] = sq;
    }
    __syncthreads();
    if (tid < 32) {
        float s = 0.f, sq = 0.f;
#pragma unroll
        for (int rb = 0; rb < 8; rb++) { s += ps[rb * 32 + tid]; sq += pq[rb * 32 + tid]; }
        atomicAdd(&stats[tid], s);
        atomicAdd(&stats[32 + tid], sq);
    }
}

// ---- BN finalize: a = g*rsqrt(var+eps), c = be - mean*a
__global__ void bnfin_kernel(const float* __restrict__ stats, const float* __restrict__ g,
                             const float* __restrict__ be, float* __restrict__ bnab) {
    int c = threadIdx.x;
    if (c >= 32) return;
    float mean = stats[c] * (1.0f / NN);
    float var  = fmaxf(stats[32 + c] * (1.0f / NN) - mean * mean, 0.f);
    float a = g[c] * rsqrtf(var + 1e-5f);
    bnab[c] = a;
    bnab[32 + c] = be[c] - mean * a;
}

// ---- pooling: segment sums of raw r3 (batch is sorted -> run-length flush, few atomics)
#define PR 128
__global__ __launch_bounds__(256) void pool_kernel(const float* __restrict__ h,
                                                   const int* __restrict__ batch,
                                                   float* __restrict__ pooled,
                                                   float* __restrict__ pcnt) {
    int t = blockIdx.x * 256 + threadIdx.x;
    int c = t & 31;
    int g = t >> 5;
    int r0 = g * PR;
    if (r0 >= NN) return;
    int r1 = min(r0 + PR, NN);
    int cur = batch[r0];
    float acc = 0.f, cn = 0.f;
    for (int rr = r0; rr < r1; rr++) {
        int b = batch[rr];
        if (b != cur) {
            atomicAdd(&pooled[cur * 32 + c], acc);
            if (c == 0) atomicAdd(&pcnt[cur], cn);
            acc = 0.f; cn = 0.f; cur = b;
        }
        acc += h[(size_t)rr * 32 + c];
        cn += 1.f;
    }
    atomicAdd(&pooled[cur * 32 + c], acc);
    if (c == 0) atomicAdd(&pcnt[cur], cn);
}

// ---- head: BN3 affine on pooled means, fc1+relu, fc2, log_softmax
__global__ __launch_bounds__(128) void head_kernel(const float* __restrict__ pooled,
                                                   const float* __restrict__ pcnt,
                                                   const float* __restrict__ bnab,
                                                   const float* __restrict__ fc1w,
                                                   const float* __restrict__ fc1b,
                                                   const float* __restrict__ fc2w,
                                                   const float* __restrict__ fc2b,
                                                   float* __restrict__ out) {
    int g = threadIdx.x;
    if (g >= BB) return;
    float inv = 1.f / fmaxf(pcnt[g], 1.f);
    float xv[32];
#pragma unroll
    for (int c = 0; c < 32; c++) xv[c] = fmaf(bnab[c], pooled[g * 32 + c] * inv, bnab[32 + c]);
    float u[32];
#pragma unroll 4
    for (int k = 0; k < 32; k++) {
        float s = fc1b[k];
#pragma unroll
        for (int c = 0; c < 32; c++) s = fmaf(xv[c], fc1w[c * 32 + k], s);
        u[k] = fmaxf(s, 0.f);
    }
    float l[8];
#pragma unroll
    for (int o = 0; o < 8; o++) {
        float s = fc2b[o];
#pragma unroll
        for (int k = 0; k < 32; k++) s = fmaf(u[k], fc2w[k * 8 + o], s);
        l[o] = s;
    }
    float m = l[0];
#pragma unroll
    for (int o = 1; o < 8; o++) m = fmaxf(m, l[o]);
    float se = 0.f;
#pragma unroll
    for (int o = 0; o < 8; o++) se += expf(l[o] - m);
    float lse = logf(se) + m;
#pragma unroll
    for (int o = 0; o < 8; o++) out[g * 8 + o] = l[o] - lse;
}

extern "C" void kernel_launch(void* const* d_in, const int* in_sizes, int n_in,
                              void* d_out, int out_size, void* d_ws, size_t ws_size,
                              hipStream_t stream) {
    const float* x    = (const float*)d_in[0];
    const int*   ei   = (const int*)d_in[1];
    const int*   batch= (const int*)d_in[2];
    const float* w1_0 = (const float*)d_in[3];
    const float* b1_0 = (const float*)d_in[4];
    const float* w2_0 = (const float*)d_in[5];
    const float* b2_0 = (const float*)d_in[6];
    const float* g_0  = (const float*)d_in[7];
    const float* be_0 = (const float*)d_in[8];
    const float* w1s  = (const float*)d_in[9];
    const float* b1s  = (const float*)d_in[10];
    const float* w2s  = (const float*)d_in[11];
    const float* b2s  = (const float*)d_in[12];
    const float* gs   = (const float*)d_in[13];
    const float* bes  = (const float*)d_in[14];
    const float* fc1w = (const float*)d_in[15];
    const float* fc1b = (const float*)d_in[16];
    const float* fc2w = (const float*)d_in[17];
    const float* fc2b = (const float*)d_in[18];
    float* out = (float*)d_out;

    char* ws = (char*)d_ws;
    float* q     = (float*)(ws + Q_OFF);
    float* agg   = (float*)(ws + AGG_OFF);
    float* h     = (float*)(ws + H_OFF);
    int*   csr   = (int*)(ws + CSR_OFF);
    int*   cnt   = (int*)(ws + CNT_OFF);
    float* stats = (float*)(ws + STATS_OFF);
    float* bnab  = (float*)(ws + BNAB_OFF);
    float* pooled= (float*)(ws + POOLED_OFF);
    float* pcnt  = (float*)(ws + PCNT_OFF);

    hipMemsetAsync(ws + CNT_OFF, 0, ZERO_BYTES, stream);
    build_csr_kernel<<<(EE + 255) / 256, 256, 0, stream>>>(ei, cnt, csr);

    const int nblk = (NN + 255) / 256;
    const int gblk = (NN * 8 + 255) / 256;

    // layer 0 (F_IN=128)
    proj_kernel<128><<<nblk, 256, 0, stream>>>(x, w1_0, b1_0, nullptr, q, agg, stats);
    gather_kernel<<<gblk, 256, 0, stream>>>((const float4*)q, csr, cnt, (float4*)agg);
    mlp_kernel<<<nblk, 256, 0, stream>>>(agg, w2_0, b2_0, h, stats);
    bnfin_kernel<<<1, 64, 0, stream>>>(stats, g_0, be_0, bnab);

    // layers 1..3 (H=32), BN of previous layer folded into projection
    for (int i = 0; i < 3; i++) {
        proj_kernel<32><<<nblk, 256, 0, stream>>>(h, w1s + i * 1024, b1s + i * 32, bnab, q, agg, stats);
        gather_kernel<<<gblk, 256, 0, stream>>>((const float4*)q, csr, cnt, (float4*)agg);
        mlp_kernel<<<nblk, 256, 0, stream>>>(agg, w2s + i * 1024, b2s + i * 32, h, stats);
        bnfin_kernel<<<1, 64, 0, stream>>>(stats, gs + i * 32, bes + i * 32, bnab);
    }

    int pthreads = ((NN + PR - 1) / PR) * 32;
    pool_kernel<<<(pthreads + 255) / 256, 256, 0, stream>>>(h, batch, pooled, pcnt);
    head_kernel<<<1, 128, 0, stream>>>(pooled, pcnt, bnab, fc1w, fc1b, fc2w, fc2b, out);
}